// Round 1
// baseline (2280.651 us; speedup 1.0000x reference)
//
#include <hip/hip_runtime.h>
#include <cstddef>

#define NN 100000
#define NE 800000
#define NG 64
#define DD 128
#define NV 8

// ---------------- utility kernels ----------------

__global__ __launch_bounds__(256) void copy_f4(const float4* __restrict__ s,
                                               float4* __restrict__ d, int n4) {
  int i = blockIdx.x * blockDim.x + threadIdx.x;
  int stride = gridDim.x * blockDim.x;
  for (; i < n4; i += stride) d[i] = s[i];
}

__global__ __launch_bounds__(256) void zero_f(float* __restrict__ p, int n) {
  int i = blockIdx.x * blockDim.x + threadIdx.x;
  if (i < n) p[i] = 0.f;
}

// ---------------- edge aggregation: agg[dst] += x[src] ----------------
// one wave (64 lanes) per edge; lane handles float2 -> 64*8B = 512B row
__global__ __launch_bounds__(256) void scatter_add(const float* __restrict__ x,
                                                   const int* __restrict__ src,
                                                   const int* __restrict__ dst,
                                                   float* __restrict__ agg) {
  int gtid = blockIdx.x * blockDim.x + threadIdx.x;
  int wave = gtid >> 6;
  int lane = threadIdx.x & 63;
  int nw = (gridDim.x * blockDim.x) >> 6;
  for (int e = wave; e < NE; e += nw) {
    int s = src[e];
    int d = dst[e];
    float2 v = *reinterpret_cast<const float2*>(x + (size_t)s * DD + lane * 2);
    float* p = agg + (size_t)d * DD + lane * 2;
    unsafeAtomicAdd(p, v.x);
    unsafeAtomicAdd(p + 1, v.y);
  }
}

// ---------------- H = relu(A @ W + b), A:[NN][128], W:[128][128] ----------------
// block: 256 threads, 32-row tile. thread (cg,rg): cols cg*4..+3, rows rg*4..+3
__global__ __launch_bounds__(256) void gemm_relu(const float* __restrict__ A,
                                                 const float* __restrict__ W,
                                                 const float* __restrict__ b,
                                                 float* __restrict__ H) {
  __shared__ float xs[32 * DD];  // 16 KB
  const int block_row = blockIdx.x * 32;
  // load 32 rows of A into LDS (1024 float4, 4 per thread)
  const float4* Asrc = reinterpret_cast<const float4*>(A + (size_t)block_row * DD);
  float4* xs4 = reinterpret_cast<float4*>(xs);
#pragma unroll
  for (int i = 0; i < 4; i++) xs4[threadIdx.x + i * 256] = Asrc[threadIdx.x + i * 256];
  __syncthreads();

  const int cg = threadIdx.x & 31;  // col group
  const int rg = threadIdx.x >> 5;  // row group (0..7)
  float acc[4][4] = {};

  for (int k = 0; k < DD; k += 4) {
    float4 wv[4];
#pragma unroll
    for (int kk = 0; kk < 4; kk++)
      wv[kk] = *reinterpret_cast<const float4*>(W + (size_t)(k + kk) * DD + cg * 4);
#pragma unroll
    for (int r = 0; r < 4; r++) {
      float4 xv = *reinterpret_cast<const float4*>(&xs[(rg * 4 + r) * DD + k]);
      acc[r][0] += xv.x * wv[0].x + xv.y * wv[1].x + xv.z * wv[2].x + xv.w * wv[3].x;
      acc[r][1] += xv.x * wv[0].y + xv.y * wv[1].y + xv.z * wv[2].y + xv.w * wv[3].y;
      acc[r][2] += xv.x * wv[0].z + xv.y * wv[1].z + xv.z * wv[2].z + xv.w * wv[3].z;
      acc[r][3] += xv.x * wv[0].w + xv.y * wv[1].w + xv.z * wv[2].w + xv.w * wv[3].w;
    }
  }

  float4 bv = *reinterpret_cast<const float4*>(b + cg * 4);
#pragma unroll
  for (int r = 0; r < 4; r++) {
    int row = block_row + rg * 4 + r;
    float4 o;
    o.x = fmaxf(acc[r][0] + bv.x, 0.f);
    o.y = fmaxf(acc[r][1] + bv.y, 0.f);
    o.z = fmaxf(acc[r][2] + bv.z, 0.f);
    o.w = fmaxf(acc[r][3] + bv.w, 0.f);
    *reinterpret_cast<float4*>(H + (size_t)row * DD + cg * 4) = o;
  }
}

// ---------------- per-graph sum (graph_id sorted) ----------------
// block: 128 threads (feature f = tid), 256 consecutive nodes per block
__global__ __launch_bounds__(128) void pool_partial(const float* __restrict__ H,
                                                    const int* __restrict__ gid,
                                                    float* __restrict__ sums,
                                                    float* __restrict__ cnts) {
  const int CHUNK = 256;
  int start = blockIdx.x * CHUNK;
  int end = start + CHUNK;
  if (end > NN) end = NN;
  if (start >= NN) return;
  int f = threadIdx.x;
  float acc = 0.f;
  int cnt = 0;
  int cur = gid[start];
  for (int n = start; n < end; n++) {
    int g = gid[n];
    if (g != cur) {
      unsafeAtomicAdd(&sums[cur * DD + f], acc);
      if (f == 0) unsafeAtomicAdd(&cnts[cur], (float)cnt);
      acc = 0.f;
      cnt = 0;
      cur = g;
    }
    acc += H[(size_t)n * DD + f];
    cnt++;
  }
  unsafeAtomicAdd(&sums[cur * DD + f], acc);
  if (f == 0) unsafeAtomicAdd(&cnts[cur], (float)cnt);
}

// ---------------- head: out[g][v] = (sums[g]/cnt) @ Wp + bp ----------------
__global__ __launch_bounds__(512) void head(const float* __restrict__ sums,
                                            const float* __restrict__ cnts,
                                            const float* __restrict__ Wp,
                                            const float* __restrict__ bp,
                                            float* __restrict__ out) {
  int t = threadIdx.x;  // 0..511
  int g = t >> 3;
  int v = t & 7;
  float cnt = cnts[g];
  if (cnt < 1.f) cnt = 1.f;
  float acc = 0.f;
  for (int d = 0; d < DD; d++) acc += sums[g * DD + d] * Wp[d * NV + v];
  out[t] = acc / cnt + bp[v];
}

// ---------------- launch ----------------
extern "C" void kernel_launch(void* const* d_in, const int* in_sizes, int n_in,
                              void* d_out, int out_size, void* d_ws, size_t ws_size,
                              hipStream_t stream) {
  const float* feat = (const float*)d_in[0];
  const int* src = (const int*)d_in[1];
  const int* dst = (const int*)d_in[2];
  const int* gid = (const int*)d_in[3];
  const float* W1 = (const float*)d_in[4];
  const float* b1 = (const float*)d_in[5];
  const float* W2 = (const float*)d_in[6];
  const float* b2 = (const float*)d_in[7];
  const float* W3 = (const float*)d_in[8];
  const float* b3 = (const float*)d_in[9];
  const float* Wp = (const float*)d_in[10];
  const float* bp = (const float*)d_in[11];
  float* out = (float*)d_out;

  char* ws = (char*)d_ws;
  const size_t mat_bytes = (size_t)NN * DD * sizeof(float);
  float* agg = (float*)ws;
  float* h = (float*)(ws + mat_bytes);
  float* sums = (float*)(ws + 2 * mat_bytes);
  float* cnts = sums + NG * DD;

  // zero pooling accumulators (ws is poisoned, not re-zeroed between replays)
  zero_f<<<(NG * DD + NG + 255) / 256, 256, 0, stream>>>(sums, NG * DD + NG);

  const int n4 = NN * DD / 4;
  const float* xin = feat;
  const float* Ws[3] = {W1, W2, W3};
  const float* bs[3] = {b1, b2, b3};
  for (int l = 0; l < 3; l++) {
    // agg = xin  (self term)
    copy_f4<<<2048, 256, 0, stream>>>((const float4*)xin, (float4*)agg, n4);
    // agg[dst] += xin[src]
    scatter_add<<<4096, 256, 0, stream>>>(xin, src, dst, agg);
    // h = relu(agg @ W + b)
    gemm_relu<<<NN / 32, 256, 0, stream>>>(agg, Ws[l], bs[l], h);
    xin = h;
  }

  pool_partial<<<(NN + 255) / 256, 128, 0, stream>>>(h, gid, sums, cnts);
  head<<<1, 512, 0, stream>>>(sums, cnts, Wp, bp, out);
}

// Round 2
// 653.430 us; speedup vs baseline: 3.4903x; 3.4903x over previous
//
#include <hip/hip_runtime.h>
#include <cstddef>

#define NN 100000
#define NE 800000
#define NG 64
#define DD 128
#define NV 8
#define SCAN_CH 1024
#define SCAN_NB ((NN + SCAN_CH - 1) / SCAN_CH)  // 98

// ---------------- utility ----------------

__global__ __launch_bounds__(256) void zero_f(float* __restrict__ p, int n) {
  int i = blockIdx.x * blockDim.x + threadIdx.x;
  if (i < n) p[i] = 0.f;
}

__global__ __launch_bounds__(256) void zero_i(int* __restrict__ p, int n) {
  int i = blockIdx.x * blockDim.x + threadIdx.x;
  if (i < n) p[i] = 0;
}

// ---------------- CSR build (once per call; src/dst fixed) ----------------

__global__ __launch_bounds__(256) void hist_dst(const int* __restrict__ dst,
                                                int* __restrict__ deg) {
  int e = blockIdx.x * blockDim.x + threadIdx.x;
  if (e < NE) atomicAdd(&deg[dst[e]], 1);
}

// per-block exclusive scan over 1024-elem chunks
__global__ __launch_bounds__(256) void scan1(const int* __restrict__ deg,
                                             int* __restrict__ excl,
                                             int* __restrict__ bsum) {
  __shared__ int ts[256];
  int base = blockIdx.x * SCAN_CH;
  int t = threadIdx.x;
  int v[4];
  int s = 0;
#pragma unroll
  for (int i = 0; i < 4; i++) {
    int idx = base + t * 4 + i;
    v[i] = (idx < NN) ? deg[idx] : 0;
    s += v[i];
  }
  ts[t] = s;
  __syncthreads();
  for (int off = 1; off < 256; off <<= 1) {
    int val = (t >= off) ? ts[t - off] : 0;
    __syncthreads();
    ts[t] += val;
    __syncthreads();
  }
  if (t == 255) bsum[blockIdx.x] = ts[255];
  int run = ts[t] - s;  // exclusive within block
#pragma unroll
  for (int i = 0; i < 4; i++) {
    int idx = base + t * 4 + i;
    if (idx < NN) excl[idx] = run;
    run += v[i];
  }
}

__global__ void scan2(int* __restrict__ bsum, int nb) {
  if (threadIdx.x == 0 && blockIdx.x == 0) {
    int run = 0;
    for (int i = 0; i < nb; i++) {
      int v = bsum[i];
      bsum[i] = run;
      run += v;
    }
  }
}

__global__ __launch_bounds__(256) void scan3(int* __restrict__ excl,
                                             const int* __restrict__ bsum,
                                             int* __restrict__ cursor) {
  int i = blockIdx.x * blockDim.x + threadIdx.x;
  if (i < NN) {
    int v = excl[i] + bsum[i / SCAN_CH];
    excl[i] = v;
    cursor[i] = v;
  }
}

__global__ __launch_bounds__(256) void fill_csr(const int* __restrict__ src,
                                                const int* __restrict__ dst,
                                                int* __restrict__ cursor,
                                                int* __restrict__ csr) {
  int e = blockIdx.x * blockDim.x + threadIdx.x;
  if (e < NE) {
    int pos = atomicAdd(&cursor[dst[e]], 1);
    csr[pos] = src[e];
  }
}

// ---------------- aggregation: agg[n] = x[n] + sum_{s in N(n)} x[s] ----------------
// one wave per node; lane handles a float2 (64*8B = 512B row)
__global__ __launch_bounds__(256) void gather_agg(const float* __restrict__ x,
                                                  const int* __restrict__ csr,
                                                  const int* __restrict__ rowp,
                                                  const int* __restrict__ deg,
                                                  float* __restrict__ agg) {
  int wib = threadIdx.x >> 6;
  int lane = threadIdx.x & 63;
  int node = blockIdx.x * (blockDim.x >> 6) + wib;
  if (node >= NN) return;
  int start = rowp[node];
  int cnt = deg[node];
  float2 acc = *reinterpret_cast<const float2*>(x + (size_t)node * DD + lane * 2);
  for (int i = 0; i < cnt; i++) {
    int s = csr[start + i];
    float2 v = *reinterpret_cast<const float2*>(x + (size_t)s * DD + lane * 2);
    acc.x += v.x;
    acc.y += v.y;
  }
  *reinterpret_cast<float2*>(agg + (size_t)node * DD + lane * 2) = acc;
}

// ---------------- H = relu(A @ W + b) ----------------
__global__ __launch_bounds__(256) void gemm_relu(const float* __restrict__ A,
                                                 const float* __restrict__ W,
                                                 const float* __restrict__ b,
                                                 float* __restrict__ H) {
  __shared__ float xs[32 * DD];
  const int block_row = blockIdx.x * 32;
  const float4* Asrc = reinterpret_cast<const float4*>(A + (size_t)block_row * DD);
  float4* xs4 = reinterpret_cast<float4*>(xs);
#pragma unroll
  for (int i = 0; i < 4; i++) xs4[threadIdx.x + i * 256] = Asrc[threadIdx.x + i * 256];
  __syncthreads();

  const int cg = threadIdx.x & 31;
  const int rg = threadIdx.x >> 5;
  float acc[4][4] = {};

  for (int k = 0; k < DD; k += 4) {
    float4 wv[4];
#pragma unroll
    for (int kk = 0; kk < 4; kk++)
      wv[kk] = *reinterpret_cast<const float4*>(W + (size_t)(k + kk) * DD + cg * 4);
#pragma unroll
    for (int r = 0; r < 4; r++) {
      float4 xv = *reinterpret_cast<const float4*>(&xs[(rg * 4 + r) * DD + k]);
      acc[r][0] += xv.x * wv[0].x + xv.y * wv[1].x + xv.z * wv[2].x + xv.w * wv[3].x;
      acc[r][1] += xv.x * wv[0].y + xv.y * wv[1].y + xv.z * wv[2].y + xv.w * wv[3].y;
      acc[r][2] += xv.x * wv[0].z + xv.y * wv[1].z + xv.z * wv[2].z + xv.w * wv[3].z;
      acc[r][3] += xv.x * wv[0].w + xv.y * wv[1].w + xv.z * wv[2].w + xv.w * wv[3].w;
    }
  }

  float4 bv = *reinterpret_cast<const float4*>(b + cg * 4);
#pragma unroll
  for (int r = 0; r < 4; r++) {
    int row = block_row + rg * 4 + r;
    float4 o;
    o.x = fmaxf(acc[r][0] + bv.x, 0.f);
    o.y = fmaxf(acc[r][1] + bv.y, 0.f);
    o.z = fmaxf(acc[r][2] + bv.z, 0.f);
    o.w = fmaxf(acc[r][3] + bv.w, 0.f);
    *reinterpret_cast<float4*>(H + (size_t)row * DD + cg * 4) = o;
  }
}

// ---------------- per-graph sum (graph_id sorted) ----------------
__global__ __launch_bounds__(128) void pool_partial(const float* __restrict__ H,
                                                    const int* __restrict__ gid,
                                                    float* __restrict__ sums,
                                                    float* __restrict__ cnts) {
  const int CHUNK = 256;
  int start = blockIdx.x * CHUNK;
  int end = start + CHUNK;
  if (end > NN) end = NN;
  if (start >= NN) return;
  int f = threadIdx.x;
  float acc = 0.f;
  int cnt = 0;
  int cur = gid[start];
  for (int n = start; n < end; n++) {
    int g = gid[n];
    if (g != cur) {
      unsafeAtomicAdd(&sums[cur * DD + f], acc);
      if (f == 0) unsafeAtomicAdd(&cnts[cur], (float)cnt);
      acc = 0.f;
      cnt = 0;
      cur = g;
    }
    acc += H[(size_t)n * DD + f];
    cnt++;
  }
  unsafeAtomicAdd(&sums[cur * DD + f], acc);
  if (f == 0) unsafeAtomicAdd(&cnts[cur], (float)cnt);
}

// ---------------- head ----------------
__global__ __launch_bounds__(512) void head(const float* __restrict__ sums,
                                            const float* __restrict__ cnts,
                                            const float* __restrict__ Wp,
                                            const float* __restrict__ bp,
                                            float* __restrict__ out) {
  int t = threadIdx.x;
  int g = t >> 3;
  int v = t & 7;
  float cnt = cnts[g];
  if (cnt < 1.f) cnt = 1.f;
  float acc = 0.f;
  for (int d = 0; d < DD; d++) acc += sums[g * DD + d] * Wp[d * NV + v];
  out[t] = acc / cnt + bp[v];
}

// ---------------- launch ----------------
extern "C" void kernel_launch(void* const* d_in, const int* in_sizes, int n_in,
                              void* d_out, int out_size, void* d_ws, size_t ws_size,
                              hipStream_t stream) {
  const float* feat = (const float*)d_in[0];
  const int* src = (const int*)d_in[1];
  const int* dst = (const int*)d_in[2];
  const int* gid = (const int*)d_in[3];
  const float* W1 = (const float*)d_in[4];
  const float* b1 = (const float*)d_in[5];
  const float* W2 = (const float*)d_in[6];
  const float* b2 = (const float*)d_in[7];
  const float* W3 = (const float*)d_in[8];
  const float* b3 = (const float*)d_in[9];
  const float* Wp = (const float*)d_in[10];
  const float* bp = (const float*)d_in[11];
  float* out = (float*)d_out;

  char* ws = (char*)d_ws;
  float* agg = (float*)ws;
  float* h = agg + (size_t)NN * DD;
  float* sums = h + (size_t)NN * DD;
  float* cnts = sums + NG * DD;
  int* deg = (int*)(cnts + NG);
  int* rowp = deg + NN;
  int* cursor = rowp + NN;
  int* bsum = cursor + NN;
  int* csr = bsum + 128;

  // zero pooling accumulators + degree histogram
  zero_f<<<(NG * DD + NG + 255) / 256, 256, 0, stream>>>(sums, NG * DD + NG);
  zero_i<<<(NN + 255) / 256, 256, 0, stream>>>(deg, NN);

  // CSR build (edges grouped by dst)
  hist_dst<<<(NE + 255) / 256, 256, 0, stream>>>(dst, deg);
  scan1<<<SCAN_NB, 256, 0, stream>>>(deg, rowp, bsum);
  scan2<<<1, 64, 0, stream>>>(bsum, SCAN_NB);
  scan3<<<(NN + 255) / 256, 256, 0, stream>>>(rowp, bsum, cursor);
  fill_csr<<<(NE + 255) / 256, 256, 0, stream>>>(src, dst, cursor, csr);

  const float* xin = feat;
  const float* Ws[3] = {W1, W2, W3};
  const float* bs[3] = {b1, b2, b3};
  for (int l = 0; l < 3; l++) {
    gather_agg<<<(NN + 3) / 4, 256, 0, stream>>>(xin, csr, rowp, deg, agg);
    gemm_relu<<<NN / 32, 256, 0, stream>>>(agg, Ws[l], bs[l], h);
    xin = h;
  }

  pool_partial<<<(NN + 255) / 256, 128, 0, stream>>>(h, gid, sums, cnts);
  head<<<1, 512, 0, stream>>>(sums, cnts, Wp, bp, out);
}

// Round 3
// 506.295 us; speedup vs baseline: 4.5046x; 1.2906x over previous
//
#include <hip/hip_runtime.h>
#include <cstddef>

#define NN 100000
#define NE 800000
#define NG 64
#define DD 128
#define NV 8
#define SCAN_CH 1024
#define SCAN_NB ((NN + SCAN_CH - 1) / SCAN_CH)  // 98

typedef __attribute__((ext_vector_type(8))) short bf16x8;
typedef __attribute__((ext_vector_type(4))) float f32x4;

// ---------------- bf16 helpers ----------------
__device__ inline float b2f(unsigned short u) {
  union { unsigned int i; float f; } x;
  x.i = ((unsigned int)u) << 16;
  return x.f;
}
__device__ inline unsigned short f2b(float f) {
  union { float f; unsigned int i; } x;
  x.f = f;
  unsigned int r = x.i + 0x7fffu + ((x.i >> 16) & 1u);
  return (unsigned short)(r >> 16);
}

// ---------------- utility ----------------
__global__ __launch_bounds__(256) void zero_f(float* __restrict__ p, int n) {
  int i = blockIdx.x * blockDim.x + threadIdx.x;
  if (i < n) p[i] = 0.f;
}
__global__ __launch_bounds__(256) void zero_i(int* __restrict__ p, int n) {
  int i = blockIdx.x * blockDim.x + threadIdx.x;
  if (i < n) p[i] = 0;
}

// features f32 -> bf16 (packed)
__global__ __launch_bounds__(256) void cvt_feat(const float4* __restrict__ s,
                                                ushort4* __restrict__ d, int n4) {
  int i = blockIdx.x * blockDim.x + threadIdx.x;
  int stride = gridDim.x * blockDim.x;
  for (; i < n4; i += stride) {
    float4 v = s[i];
    ushort4 o;
    o.x = f2b(v.x); o.y = f2b(v.y); o.z = f2b(v.z); o.w = f2b(v.w);
    d[i] = o;
  }
}

// W[k][n] f32 -> Wt[n][k] bf16
__global__ __launch_bounds__(256) void cvt_wt(const float* __restrict__ W,
                                              unsigned short* __restrict__ Wt) {
  int idx = blockIdx.x * blockDim.x + threadIdx.x;  // 16384
  int n = idx >> 7, k = idx & 127;
  Wt[idx] = f2b(W[k * DD + n]);
}

// ---------------- CSR build ----------------
__global__ __launch_bounds__(256) void hist_dst(const int* __restrict__ dst,
                                                int* __restrict__ deg) {
  int e = blockIdx.x * blockDim.x + threadIdx.x;
  if (e < NE) atomicAdd(&deg[dst[e]], 1);
}

__global__ __launch_bounds__(256) void scan1(const int* __restrict__ deg,
                                             int* __restrict__ excl,
                                             int* __restrict__ bsum) {
  __shared__ int ts[256];
  int base = blockIdx.x * SCAN_CH;
  int t = threadIdx.x;
  int v[4];
  int s = 0;
#pragma unroll
  for (int i = 0; i < 4; i++) {
    int idx = base + t * 4 + i;
    v[i] = (idx < NN) ? deg[idx] : 0;
    s += v[i];
  }
  ts[t] = s;
  __syncthreads();
  for (int off = 1; off < 256; off <<= 1) {
    int val = (t >= off) ? ts[t - off] : 0;
    __syncthreads();
    ts[t] += val;
    __syncthreads();
  }
  if (t == 255) bsum[blockIdx.x] = ts[255];
  int run = ts[t] - s;
#pragma unroll
  for (int i = 0; i < 4; i++) {
    int idx = base + t * 4 + i;
    if (idx < NN) excl[idx] = run;
    run += v[i];
  }
}

__global__ void scan2(int* __restrict__ bsum, int nb) {
  if (threadIdx.x == 0 && blockIdx.x == 0) {
    int run = 0;
    for (int i = 0; i < nb; i++) {
      int v = bsum[i];
      bsum[i] = run;
      run += v;
    }
  }
}

__global__ __launch_bounds__(256) void scan3(int* __restrict__ excl,
                                             const int* __restrict__ bsum,
                                             int* __restrict__ cursor) {
  int i = blockIdx.x * blockDim.x + threadIdx.x;
  if (i < NN) {
    int v = excl[i] + bsum[i / SCAN_CH];
    excl[i] = v;
    cursor[i] = v;
  }
}

__global__ __launch_bounds__(256) void fill_csr(const int* __restrict__ src,
                                                const int* __restrict__ dst,
                                                int* __restrict__ cursor,
                                                int* __restrict__ csr) {
  int e = blockIdx.x * blockDim.x + threadIdx.x;
  if (e < NE) {
    int pos = atomicAdd(&cursor[dst[e]], 1);
    csr[pos] = src[e];
  }
}

// ---------------- bf16 gather: agg[n] = x[n] + sum x[nbr] ----------------
// wave per node; lane handles one uint = 2 bf16 (64*4B = 256B row)
__global__ __launch_bounds__(256) void gather_agg_b(const unsigned int* __restrict__ x,
                                                    const int* __restrict__ csr,
                                                    const int* __restrict__ rowp,
                                                    const int* __restrict__ deg,
                                                    unsigned int* __restrict__ agg) {
  int wib = threadIdx.x >> 6;
  int lane = threadIdx.x & 63;
  int node = blockIdx.x * 4 + wib;
  if (node >= NN) return;
  int start = rowp[node];
  int cnt = deg[node];
  unsigned int sv = x[(size_t)node * 64 + lane];
  float ax = b2f((unsigned short)(sv & 0xffff));
  float ay = b2f((unsigned short)(sv >> 16));
  for (int i = 0; i < cnt; i++) {
    int s = csr[start + i];
    unsigned int v = x[(size_t)s * 64 + lane];
    ax += b2f((unsigned short)(v & 0xffff));
    ay += b2f((unsigned short)(v >> 16));
  }
  agg[(size_t)node * 64 + lane] = (unsigned int)f2b(ax) | ((unsigned int)f2b(ay) << 16);
}

// ---------------- H = relu(A @ W + b) via MFMA, bf16 in/out ----------------
// 256 threads = 4 waves; 64-row tile; each wave computes 16 rows x 128 cols
__global__ __launch_bounds__(256) void gemm_mfma(const unsigned short* __restrict__ A,
                                                 const unsigned short* __restrict__ Wt,
                                                 const float* __restrict__ bias,
                                                 unsigned short* __restrict__ H) {
  __shared__ uint4 a_sh4[1024];  // 16KB: A tile [64][256B] swizzled
  __shared__ uint4 w_sh4[2048];  // 32KB: Wt [128][256B] swizzled; reused as f32 out [64][128]
  char* a_sh = (char*)a_sh4;
  char* w_sh = (char*)w_sh4;
  const int t = threadIdx.x;
  const int block_row = blockIdx.x * 64;

  // stage A tile (4 passes of 4KB)
#pragma unroll
  for (int p = 0; p < 4; p++) {
    int lin = p * 4096 + t * 16;
    int row = lin >> 8, inner = lin & 255;
    int grow = block_row + row;
    uint4 v = make_uint4(0u, 0u, 0u, 0u);
    if (grow < NN) v = *(const uint4*)((const char*)A + (size_t)grow * 256 + inner);
    *(uint4*)(a_sh + row * 256 + (inner ^ ((row & 7) << 4))) = v;
  }
  // stage Wt (8 passes)
#pragma unroll
  for (int p = 0; p < 8; p++) {
    int lin = p * 4096 + t * 16;
    int row = lin >> 8, inner = lin & 255;
    uint4 v = *(const uint4*)((const char*)Wt + lin);
    *(uint4*)(w_sh + row * 256 + (inner ^ ((row & 7) << 4))) = v;
  }
  __syncthreads();

  const int wid = t >> 6, lane = t & 63;
  const int rowbase = wid * 16;
  const int lr = lane & 15, lk = lane >> 4;

  f32x4 acc[8];
#pragma unroll
  for (int i = 0; i < 8; i++) acc[i] = (f32x4){0.f, 0.f, 0.f, 0.f};

#pragma unroll
  for (int c = 0; c < 4; c++) {
    int arow = rowbase + lr;
    bf16x8 af = *(const bf16x8*)(a_sh + arow * 256 + ((c * 64 + lk * 16) ^ ((arow & 7) << 4)));
#pragma unroll
    for (int nt = 0; nt < 8; nt++) {
      int bcol = nt * 16 + lr;
      bf16x8 bf = *(const bf16x8*)(w_sh + bcol * 256 + ((c * 64 + lk * 16) ^ ((bcol & 7) << 4)));
      acc[nt] = __builtin_amdgcn_mfma_f32_16x16x32_bf16(af, bf, acc[nt], 0, 0, 0);
    }
  }
  __syncthreads();  // all waves done reading w_sh

  // bias + relu, stage f32 output in w_sh as [64][128] f32
  float* osh = (float*)w_sh;
#pragma unroll
  for (int nt = 0; nt < 8; nt++) {
    int col = nt * 16 + lr;
    float bv = bias[col];
#pragma unroll
    for (int r = 0; r < 4; r++) {
      int row = rowbase + lk * 4 + r;
      osh[row * 128 + col] = fmaxf(acc[nt][r] + bv, 0.f);
    }
  }
  __syncthreads();

  // linear read, convert to bf16, coalesced store
#pragma unroll
  for (int i = 0; i < 8; i++) {
    int fidx = i * 1024 + t * 4;
    float4 v = *(const float4*)(osh + fidx);
    int row = fidx >> 7, col = fidx & 127;
    int grow = block_row + row;
    if (grow < NN) {
      ushort4 o;
      o.x = f2b(v.x); o.y = f2b(v.y); o.z = f2b(v.z); o.w = f2b(v.w);
      *(ushort4*)((char*)H + (size_t)grow * 256 + col * 2) = o;
    }
  }
}

// ---------------- per-graph sum (bf16 input, sorted graph_id) ----------------
__global__ __launch_bounds__(128) void pool_partial(const unsigned short* __restrict__ H,
                                                    const int* __restrict__ gid,
                                                    float* __restrict__ sums,
                                                    float* __restrict__ cnts) {
  const int CHUNK = 256;
  int start = blockIdx.x * CHUNK;
  int end = start + CHUNK;
  if (end > NN) end = NN;
  if (start >= NN) return;
  int f = threadIdx.x;
  float acc = 0.f;
  int cnt = 0;
  int cur = gid[start];
  for (int n = start; n < end; n++) {
    int g = gid[n];
    if (g != cur) {
      unsafeAtomicAdd(&sums[cur * DD + f], acc);
      if (f == 0) unsafeAtomicAdd(&cnts[cur], (float)cnt);
      acc = 0.f;
      cnt = 0;
      cur = g;
    }
    acc += b2f(H[(size_t)n * DD + f]);
    cnt++;
  }
  unsafeAtomicAdd(&sums[cur * DD + f], acc);
  if (f == 0) unsafeAtomicAdd(&cnts[cur], (float)cnt);
}

// ---------------- head ----------------
__global__ __launch_bounds__(512) void head(const float* __restrict__ sums,
                                            const float* __restrict__ cnts,
                                            const float* __restrict__ Wp,
                                            const float* __restrict__ bp,
                                            float* __restrict__ out) {
  int t = threadIdx.x;
  int g = t >> 3;
  int v = t & 7;
  float cnt = cnts[g];
  if (cnt < 1.f) cnt = 1.f;
  float acc = 0.f;
  for (int d = 0; d < DD; d++) acc += sums[g * DD + d] * Wp[d * NV + v];
  out[t] = acc / cnt + bp[v];
}

// ---------------- launch ----------------
extern "C" void kernel_launch(void* const* d_in, const int* in_sizes, int n_in,
                              void* d_out, int out_size, void* d_ws, size_t ws_size,
                              hipStream_t stream) {
  const float* feat = (const float*)d_in[0];
  const int* src = (const int*)d_in[1];
  const int* dst = (const int*)d_in[2];
  const int* gid = (const int*)d_in[3];
  const float* W1 = (const float*)d_in[4];
  const float* b1 = (const float*)d_in[5];
  const float* W2 = (const float*)d_in[6];
  const float* b2 = (const float*)d_in[7];
  const float* W3 = (const float*)d_in[8];
  const float* b3 = (const float*)d_in[9];
  const float* Wp = (const float*)d_in[10];
  const float* bp = (const float*)d_in[11];
  float* out = (float*)d_out;

  char* ws = (char*)d_ws;
  const size_t matb = (size_t)NN * DD;  // elements per matrix
  unsigned short* xb = (unsigned short*)ws;
  unsigned short* aggb = xb + matb;
  unsigned short* hb = aggb + matb;
  unsigned short* wtb = hb + matb;  // 3 * 16384
  float* sums = (float*)(wtb + 3 * DD * DD);
  float* cnts = sums + NG * DD;
  int* deg = (int*)(cnts + NG);
  int* rowp = deg + NN;
  int* cursor = rowp + NN;
  int* bsum = cursor + NN;
  int* csr = bsum + 128;

  zero_f<<<(NG * DD + NG + 255) / 256, 256, 0, stream>>>(sums, NG * DD + NG);
  zero_i<<<(NN + 255) / 256, 256, 0, stream>>>(deg, NN);

  // conversions
  cvt_feat<<<2048, 256, 0, stream>>>((const float4*)feat, (ushort4*)xb, NN * DD / 4);
  cvt_wt<<<64, 256, 0, stream>>>(W1, wtb);
  cvt_wt<<<64, 256, 0, stream>>>(W2, wtb + DD * DD);
  cvt_wt<<<64, 256, 0, stream>>>(W3, wtb + 2 * DD * DD);

  // CSR build
  hist_dst<<<(NE + 255) / 256, 256, 0, stream>>>(dst, deg);
  scan1<<<SCAN_NB, 256, 0, stream>>>(deg, rowp, bsum);
  scan2<<<1, 64, 0, stream>>>(bsum, SCAN_NB);
  scan3<<<(NN + 255) / 256, 256, 0, stream>>>(rowp, bsum, cursor);
  fill_csr<<<(NE + 255) / 256, 256, 0, stream>>>(src, dst, cursor, csr);

  const float* bs[3] = {b1, b2, b3};
  // ping-pong: L1 xb->hb, L2 hb->xb, L3 xb->hb
  const unsigned short* xin = xb;
  unsigned short* xout = hb;
  for (int l = 0; l < 3; l++) {
    gather_agg_b<<<(NN + 3) / 4, 256, 0, stream>>>((const unsigned int*)xin, csr, rowp, deg,
                                                   (unsigned int*)aggb);
    gemm_mfma<<<(NN + 63) / 64, 256, 0, stream>>>(aggb, wtb + l * DD * DD, bs[l], xout);
    const unsigned short* tmp = xout;
    xout = (unsigned short*)(l == 0 ? xb : hb);
    xin = tmp;
  }

  pool_partial<<<(NN + 255) / 256, 128, 0, stream>>>(hb, gid, sums, cnts);
  head<<<1, 512, 0, stream>>>(sums, cnts, Wp, bp, out);
}

// Round 4
// 505.825 us; speedup vs baseline: 4.5088x; 1.0009x over previous
//
#include <hip/hip_runtime.h>
#include <cstddef>

#define NN 100000
#define NE 800000
#define NG 64
#define DD 128
#define NV 8
#define SCAN_CH 1024
#define SCAN_NB ((NN + SCAN_CH - 1) / SCAN_CH)  // 98

typedef __attribute__((ext_vector_type(8))) short bf16x8;
typedef __attribute__((ext_vector_type(4))) float f32x4;

// ---------------- bf16 helpers ----------------
__device__ inline float b2f(unsigned short u) {
  union { unsigned int i; float f; } x;
  x.i = ((unsigned int)u) << 16;
  return x.f;
}
__device__ inline unsigned short f2b(float f) {
  union { float f; unsigned int i; } x;
  x.f = f;
  unsigned int r = x.i + 0x7fffu + ((x.i >> 16) & 1u);
  return (unsigned short)(r >> 16);
}

// ---------------- utility ----------------
__global__ __launch_bounds__(256) void zero_f(float* __restrict__ p, int n) {
  int i = blockIdx.x * blockDim.x + threadIdx.x;
  if (i < n) p[i] = 0.f;
}
__global__ __launch_bounds__(256) void zero_i(int* __restrict__ p, int n) {
  int i = blockIdx.x * blockDim.x + threadIdx.x;
  if (i < n) p[i] = 0;
}

// features f32 -> bf16 (packed)
__global__ __launch_bounds__(256) void cvt_feat(const float4* __restrict__ s,
                                                ushort4* __restrict__ d, int n4) {
  int i = blockIdx.x * blockDim.x + threadIdx.x;
  int stride = gridDim.x * blockDim.x;
  for (; i < n4; i += stride) {
    float4 v = s[i];
    ushort4 o;
    o.x = f2b(v.x); o.y = f2b(v.y); o.z = f2b(v.z); o.w = f2b(v.w);
    d[i] = o;
  }
}

// W[k][n] f32 -> Wt[n][k] bf16
__global__ __launch_bounds__(256) void cvt_wt(const float* __restrict__ W,
                                              unsigned short* __restrict__ Wt) {
  int idx = blockIdx.x * blockDim.x + threadIdx.x;  // 16384
  int n = idx >> 7, k = idx & 127;
  Wt[idx] = f2b(W[k * DD + n]);
}

// ---------------- CSR build ----------------
__global__ __launch_bounds__(256) void hist_dst(const int* __restrict__ dst,
                                                int* __restrict__ deg) {
  int e = blockIdx.x * blockDim.x + threadIdx.x;
  if (e < NE) atomicAdd(&deg[dst[e]], 1);
}

__global__ __launch_bounds__(256) void scan1(const int* __restrict__ deg,
                                             int* __restrict__ excl,
                                             int* __restrict__ bsum) {
  __shared__ int ts[256];
  int base = blockIdx.x * SCAN_CH;
  int t = threadIdx.x;
  int v[4];
  int s = 0;
#pragma unroll
  for (int i = 0; i < 4; i++) {
    int idx = base + t * 4 + i;
    v[i] = (idx < NN) ? deg[idx] : 0;
    s += v[i];
  }
  ts[t] = s;
  __syncthreads();
  for (int off = 1; off < 256; off <<= 1) {
    int val = (t >= off) ? ts[t - off] : 0;
    __syncthreads();
    ts[t] += val;
    __syncthreads();
  }
  if (t == 255) bsum[blockIdx.x] = ts[255];
  int run = ts[t] - s;
#pragma unroll
  for (int i = 0; i < 4; i++) {
    int idx = base + t * 4 + i;
    if (idx < NN) excl[idx] = run;
    run += v[i];
  }
}

__global__ void scan2(int* __restrict__ bsum, int nb) {
  if (threadIdx.x == 0 && blockIdx.x == 0) {
    int run = 0;
    for (int i = 0; i < nb; i++) {
      int v = bsum[i];
      bsum[i] = run;
      run += v;
    }
  }
}

// rowp has NN+1 entries (sentinel = NE)
__global__ __launch_bounds__(256) void scan3(int* __restrict__ rowp,
                                             const int* __restrict__ bsum,
                                             int* __restrict__ cursor) {
  int i = blockIdx.x * blockDim.x + threadIdx.x;
  if (i < NN) {
    int v = rowp[i] + bsum[i / SCAN_CH];
    rowp[i] = v;
    cursor[i] = v;
  }
  if (i == 0) rowp[NN] = NE;
}

__global__ __launch_bounds__(256) void fill_csr(const int* __restrict__ src,
                                                const int* __restrict__ dst,
                                                int* __restrict__ cursor,
                                                int* __restrict__ csr) {
  int e = blockIdx.x * blockDim.x + threadIdx.x;
  if (e < NE) {
    int pos = atomicAdd(&cursor[dst[e]], 1);
    csr[pos] = src[e];
  }
}

// ---------------- fused GIN layer: H = relu((x + sum_nbr x) @ W + b) ----------------
// 256 threads = 4 waves; 64-row tile. Wave w gathers rows w*16..w*16+15 into LDS
// (f32 accumulate, bf16 pack, XOR-swizzled), then MFMA vs LDS-staged Wt.
__global__ __launch_bounds__(256) void gin_layer(const unsigned int* __restrict__ x,
                                                 const int* __restrict__ csr,
                                                 const int* __restrict__ rowp,
                                                 const unsigned short* __restrict__ Wt,
                                                 const float* __restrict__ bias,
                                                 unsigned short* __restrict__ H) {
  __shared__ uint4 a_sh4[1024];  // 16KB: A tile [64][256B] swizzled
  __shared__ uint4 w_sh4[2048];  // 32KB: Wt [128][256B] swizzled; reused as f32 out
  char* a_sh = (char*)a_sh4;
  char* w_sh = (char*)w_sh4;
  const int t = threadIdx.x;
  const int block_row = blockIdx.x * 64;

  // stage Wt (8 passes of 4KB)
#pragma unroll
  for (int p = 0; p < 8; p++) {
    int lin = p * 4096 + t * 16;
    int row = lin >> 8, inner = lin & 255;
    uint4 v = *(const uint4*)((const char*)Wt + lin);
    *(uint4*)(w_sh + row * 256 + (inner ^ ((row & 7) << 4))) = v;
  }

  const int wid = t >> 6, lane = t & 63;

  // gather-aggregate: wave wid builds rows [wid*16, wid*16+16)
  for (int r = wid * 16; r < wid * 16 + 16; r++) {
    int node = block_row + r;
    float ax = 0.f, ay = 0.f;
    if (node < NN) {
      unsigned int sv = x[(size_t)node * 64 + lane];
      ax = b2f((unsigned short)(sv & 0xffff));
      ay = b2f((unsigned short)(sv >> 16));
      int start = rowp[node];
      int cnt = rowp[node + 1] - start;
      int i = 0;
      while (i < cnt) {
        int nload = min(cnt - i, 64);
        int idx = (lane < nload) ? csr[start + i + lane] : 0;
        int j = 0;
        for (; j + 4 <= nload; j += 4) {
          int s0 = __shfl(idx, j);
          int s1 = __shfl(idx, j + 1);
          int s2 = __shfl(idx, j + 2);
          int s3 = __shfl(idx, j + 3);
          unsigned int v0 = x[(size_t)s0 * 64 + lane];
          unsigned int v1 = x[(size_t)s1 * 64 + lane];
          unsigned int v2 = x[(size_t)s2 * 64 + lane];
          unsigned int v3 = x[(size_t)s3 * 64 + lane];
          ax += b2f((unsigned short)(v0 & 0xffff)) + b2f((unsigned short)(v1 & 0xffff)) +
                b2f((unsigned short)(v2 & 0xffff)) + b2f((unsigned short)(v3 & 0xffff));
          ay += b2f((unsigned short)(v0 >> 16)) + b2f((unsigned short)(v1 >> 16)) +
                b2f((unsigned short)(v2 >> 16)) + b2f((unsigned short)(v3 >> 16));
        }
        for (; j < nload; j++) {
          int s = __shfl(idx, j);
          unsigned int v = x[(size_t)s * 64 + lane];
          ax += b2f((unsigned short)(v & 0xffff));
          ay += b2f((unsigned short)(v >> 16));
        }
        i += nload;
      }
    }
    unsigned int packed = (unsigned int)f2b(ax) | ((unsigned int)f2b(ay) << 16);
    *(unsigned int*)(a_sh + r * 256 + ((lane * 4) ^ ((r & 7) << 4))) = packed;
  }
  __syncthreads();

  const int rowbase = wid * 16;
  const int lr = lane & 15, lk = lane >> 4;

  f32x4 acc[8];
#pragma unroll
  for (int i = 0; i < 8; i++) acc[i] = (f32x4){0.f, 0.f, 0.f, 0.f};

#pragma unroll
  for (int c = 0; c < 4; c++) {
    int arow = rowbase + lr;
    bf16x8 af = *(const bf16x8*)(a_sh + arow * 256 + ((c * 64 + lk * 16) ^ ((arow & 7) << 4)));
#pragma unroll
    for (int nt = 0; nt < 8; nt++) {
      int bcol = nt * 16 + lr;
      bf16x8 bf = *(const bf16x8*)(w_sh + bcol * 256 + ((c * 64 + lk * 16) ^ ((bcol & 7) << 4)));
      acc[nt] = __builtin_amdgcn_mfma_f32_16x16x32_bf16(af, bf, acc[nt], 0, 0, 0);
    }
  }
  __syncthreads();  // all waves done reading w_sh

  // bias + relu, stage f32 output in w_sh as [64][128]
  float* osh = (float*)w_sh;
#pragma unroll
  for (int nt = 0; nt < 8; nt++) {
    int col = nt * 16 + lr;
    float bv = bias[col];
#pragma unroll
    for (int r = 0; r < 4; r++) {
      int row = rowbase + lk * 4 + r;
      osh[row * 128 + col] = fmaxf(acc[nt][r] + bv, 0.f);
    }
  }
  __syncthreads();

  // linear read, convert to bf16, coalesced store
#pragma unroll
  for (int i = 0; i < 8; i++) {
    int fidx = i * 1024 + t * 4;
    float4 v = *(const float4*)(osh + fidx);
    int row = fidx >> 7, col = fidx & 127;
    int grow = block_row + row;
    if (grow < NN) {
      ushort4 o;
      o.x = f2b(v.x); o.y = f2b(v.y); o.z = f2b(v.z); o.w = f2b(v.w);
      *(ushort4*)((char*)H + (size_t)grow * 256 + col * 2) = o;
    }
  }
}

// ---------------- per-graph sum (bf16 input, sorted graph_id) ----------------
__global__ __launch_bounds__(128) void pool_partial(const unsigned short* __restrict__ H,
                                                    const int* __restrict__ gid,
                                                    float* __restrict__ sums,
                                                    float* __restrict__ cnts) {
  const int CHUNK = 256;
  int start = blockIdx.x * CHUNK;
  int end = start + CHUNK;
  if (end > NN) end = NN;
  if (start >= NN) return;
  int f = threadIdx.x;
  float acc = 0.f;
  int cnt = 0;
  int cur = gid[start];
  for (int n = start; n < end; n++) {
    int g = gid[n];
    if (g != cur) {
      unsafeAtomicAdd(&sums[cur * DD + f], acc);
      if (f == 0) unsafeAtomicAdd(&cnts[cur], (float)cnt);
      acc = 0.f;
      cnt = 0;
      cur = g;
    }
    acc += b2f(H[(size_t)n * DD + f]);
    cnt++;
  }
  unsafeAtomicAdd(&sums[cur * DD + f], acc);
  if (f == 0) unsafeAtomicAdd(&cnts[cur], (float)cnt);
}

// ---------------- head ----------------
__global__ __launch_bounds__(512) void head(const float* __restrict__ sums,
                                            const float* __restrict__ cnts,
                                            const float* __restrict__ Wp,
                                            const float* __restrict__ bp,
                                            float* __restrict__ out) {
  int t = threadIdx.x;
  int g = t >> 3;
  int v = t & 7;
  float cnt = cnts[g];
  if (cnt < 1.f) cnt = 1.f;
  float acc = 0.f;
  for (int d = 0; d < DD; d++) acc += sums[g * DD + d] * Wp[d * NV + v];
  out[t] = acc / cnt + bp[v];
}

// ---------------- launch ----------------
extern "C" void kernel_launch(void* const* d_in, const int* in_sizes, int n_in,
                              void* d_out, int out_size, void* d_ws, size_t ws_size,
                              hipStream_t stream) {
  const float* feat = (const float*)d_in[0];
  const int* src = (const int*)d_in[1];
  const int* dst = (const int*)d_in[2];
  const int* gid = (const int*)d_in[3];
  const float* W1 = (const float*)d_in[4];
  const float* b1 = (const float*)d_in[5];
  const float* W2 = (const float*)d_in[6];
  const float* b2 = (const float*)d_in[7];
  const float* W3 = (const float*)d_in[8];
  const float* b3 = (const float*)d_in[9];
  const float* Wp = (const float*)d_in[10];
  const float* bp = (const float*)d_in[11];
  float* out = (float*)d_out;

  char* ws = (char*)d_ws;
  const size_t matb = (size_t)NN * DD;  // elements per bf16 matrix
  unsigned short* xb = (unsigned short*)ws;
  unsigned short* hb = xb + matb;
  unsigned short* wtb = hb + matb;  // 3 * 16384
  float* sums = (float*)(wtb + 3 * DD * DD);
  float* cnts = sums + NG * DD;
  int* deg = (int*)(cnts + NG);
  int* rowp = deg + NN;          // NN+1 entries
  int* cursor = rowp + NN + 1;
  int* bsum = cursor + NN;
  int* csr = bsum + 128;

  zero_f<<<(NG * DD + NG + 255) / 256, 256, 0, stream>>>(sums, NG * DD + NG);
  zero_i<<<(NN + 255) / 256, 256, 0, stream>>>(deg, NN);

  // conversions
  cvt_feat<<<2048, 256, 0, stream>>>((const float4*)feat, (ushort4*)xb, NN * DD / 4);
  cvt_wt<<<64, 256, 0, stream>>>(W1, wtb);
  cvt_wt<<<64, 256, 0, stream>>>(W2, wtb + DD * DD);
  cvt_wt<<<64, 256, 0, stream>>>(W3, wtb + 2 * DD * DD);

  // CSR build (edges grouped by dst)
  hist_dst<<<(NE + 255) / 256, 256, 0, stream>>>(dst, deg);
  scan1<<<SCAN_NB, 256, 0, stream>>>(deg, rowp, bsum);
  scan2<<<1, 64, 0, stream>>>(bsum, SCAN_NB);
  scan3<<<(NN + 255) / 256, 256, 0, stream>>>(rowp, bsum, cursor);
  fill_csr<<<(NE + 255) / 256, 256, 0, stream>>>(src, dst, cursor, csr);

  const float* bs[3] = {b1, b2, b3};
  const int ngrid = (NN + 63) / 64;
  // ping-pong: L1 xb->hb, L2 hb->xb, L3 xb->hb
  gin_layer<<<ngrid, 256, 0, stream>>>((const unsigned int*)xb, csr, rowp, wtb, bs[0], hb);
  gin_layer<<<ngrid, 256, 0, stream>>>((const unsigned int*)hb, csr, rowp, wtb + DD * DD, bs[1], xb);
  gin_layer<<<ngrid, 256, 0, stream>>>((const unsigned int*)xb, csr, rowp, wtb + 2 * DD * DD, bs[2], hb);

  pool_partial<<<(NN + 255) / 256, 128, 0, stream>>>(hb, gid, sums, cnts);
  head<<<1, 512, 0, stream>>>(sums, cnts, Wp, bp, out);
}

// Round 5
// 425.891 us; speedup vs baseline: 5.3550x; 1.1877x over previous
//
#include <hip/hip_runtime.h>
#include <cstddef>

#define NN 100000
#define NE 800000
#define NG 64
#define DD 128
#define NV 8
#define NS 8           // column slices (16 bf16 = 32B each)
#define SCAN_CH 1024
#define SCAN_NB ((NN + SCAN_CH - 1) / SCAN_CH)  // 98
#define NPC 512        // dst nodes per gather chunk
#define NCHUNK ((NN + NPC - 1) / NPC)           // 196

typedef __attribute__((ext_vector_type(8))) short bf16x8;
typedef __attribute__((ext_vector_type(4))) float f32x4;

// ---------------- bf16 helpers ----------------
__device__ inline float b2f(unsigned short u) {
  union { unsigned int i; float f; } x;
  x.i = ((unsigned int)u) << 16;
  return x.f;
}
__device__ inline unsigned short f2b(float f) {
  union { float f; unsigned int i; } x;
  x.f = f;
  unsigned int r = x.i + 0x7fffu + ((x.i >> 16) & 1u);
  return (unsigned short)(r >> 16);
}

// ---------------- utility ----------------
__global__ __launch_bounds__(256) void zero_f(float* __restrict__ p, int n) {
  int i = blockIdx.x * blockDim.x + threadIdx.x;
  if (i < n) p[i] = 0.f;
}
__global__ __launch_bounds__(256) void zero_i(int* __restrict__ p, int n) {
  int i = blockIdx.x * blockDim.x + threadIdx.x;
  if (i < n) p[i] = 0;
}

// features f32 -> bf16, slice-major layout xs[s][n][16 bf16]
__global__ __launch_bounds__(256) void cvt_feat(const float* __restrict__ feat,
                                                unsigned int* __restrict__ xs) {
  int tid = blockIdx.x * 256 + threadIdx.x;  // NN*NS = 800000
  if (tid >= NN * NS) return;
  int n = tid >> 3, s = tid & 7;
  const float* p = feat + (size_t)n * DD + s * 16;
  unsigned int u[8];
#pragma unroll
  for (int i = 0; i < 8; i++) {
    u[i] = (unsigned int)f2b(p[2 * i]) | ((unsigned int)f2b(p[2 * i + 1]) << 16);
  }
  unsigned int* q = xs + ((size_t)s * NN + n) * 8;
  *(uint4*)q = make_uint4(u[0], u[1], u[2], u[3]);
  *(uint4*)(q + 4) = make_uint4(u[4], u[5], u[6], u[7]);
}

// all three W[k][n] f32 -> Wt[n][k] bf16 in one launch
__global__ __launch_bounds__(256) void cvt_wt3(const float* __restrict__ W1,
                                               const float* __restrict__ W2,
                                               const float* __restrict__ W3,
                                               unsigned short* __restrict__ Wt) {
  int idx = blockIdx.x * 256 + threadIdx.x;  // 3*16384
  int w = idx >> 14, r = idx & 16383;
  const float* W = (w == 0) ? W1 : (w == 1) ? W2 : W3;
  int n = r >> 7, k = r & 127;
  Wt[idx] = f2b(W[k * DD + n]);
}

// ---------------- CSR build ----------------
__global__ __launch_bounds__(256) void hist_dst(const int* __restrict__ dst,
                                                int* __restrict__ deg) {
  int e = blockIdx.x * blockDim.x + threadIdx.x;
  if (e < NE) atomicAdd(&deg[dst[e]], 1);
}

__global__ __launch_bounds__(256) void scan1(const int* __restrict__ deg,
                                             int* __restrict__ excl,
                                             int* __restrict__ bsum) {
  __shared__ int ts[256];
  int base = blockIdx.x * SCAN_CH;
  int t = threadIdx.x;
  int v[4];
  int s = 0;
#pragma unroll
  for (int i = 0; i < 4; i++) {
    int idx = base + t * 4 + i;
    v[i] = (idx < NN) ? deg[idx] : 0;
    s += v[i];
  }
  ts[t] = s;
  __syncthreads();
  for (int off = 1; off < 256; off <<= 1) {
    int val = (t >= off) ? ts[t - off] : 0;
    __syncthreads();
    ts[t] += val;
    __syncthreads();
  }
  if (t == 255) bsum[blockIdx.x] = ts[255];
  int run = ts[t] - s;
#pragma unroll
  for (int i = 0; i < 4; i++) {
    int idx = base + t * 4 + i;
    if (idx < NN) excl[idx] = run;
    run += v[i];
  }
}

// parallel scan of the 98 block sums (was a 1-thread serial loop = ~30us)
__global__ __launch_bounds__(128) void scan2(int* __restrict__ bsum, int nb) {
  __shared__ int sh[128];
  int t = threadIdx.x;
  int v = (t < nb) ? bsum[t] : 0;
  sh[t] = v;
  __syncthreads();
  for (int off = 1; off < 128; off <<= 1) {
    int u = (t >= off) ? sh[t - off] : 0;
    __syncthreads();
    sh[t] += u;
    __syncthreads();
  }
  if (t < nb) bsum[t] = sh[t] - v;  // exclusive
}

// rowp has NN+1 entries (sentinel = NE)
__global__ __launch_bounds__(256) void scan3(int* __restrict__ rowp,
                                             const int* __restrict__ bsum,
                                             int* __restrict__ cursor) {
  int i = blockIdx.x * blockDim.x + threadIdx.x;
  if (i < NN) {
    int v = rowp[i] + bsum[i / SCAN_CH];
    rowp[i] = v;
    cursor[i] = v;
  }
  if (i == 0) rowp[NN] = NE;
}

__global__ __launch_bounds__(256) void fill_csr(const int* __restrict__ src,
                                                const int* __restrict__ dst,
                                                int* __restrict__ cursor,
                                                int* __restrict__ csr) {
  int e = blockIdx.x * blockDim.x + threadIdx.x;
  if (e < NE) {
    int pos = atomicAdd(&cursor[dst[e]], 1);
    csr[pos] = src[e];
  }
}

// ---------------- sliced gather: aggs[s][n] = xs[s][n] + sum_nbr xs[s][nbr] ----------------
// slice = blockIdx.x & 7 -> pins each slice to one XCD (round-robin dispatch),
// so the 3.2MB slice stays resident in that XCD's 4MB L2.
// 8-lane groups: lane li owns 4B (2 bf16) of the 32B node-chunk.
__global__ __launch_bounds__(256) void gather_slice(const unsigned int* __restrict__ xs,
                                                    const int* __restrict__ csr,
                                                    const int* __restrict__ rowp,
                                                    unsigned int* __restrict__ aggs) {
  const int s = blockIdx.x & 7;
  const int chunk = blockIdx.x >> 3;
  const unsigned int* __restrict__ xsl = xs + (size_t)s * NN * 8;
  unsigned int* __restrict__ asl = aggs + (size_t)s * NN * 8;
  const int li = threadIdx.x & 7;
  const int grp = threadIdx.x >> 3;  // 0..31
  const int node0 = chunk * NPC;
  const int node1 = (node0 + NPC < NN) ? node0 + NPC : NN;
  for (int n = node0 + grp; n < node1; n += 32) {
    int beg = rowp[n], end = rowp[n + 1];
    unsigned int sv = xsl[(size_t)n * 8 + li];
    float ax = b2f((unsigned short)(sv & 0xffff));
    float ay = b2f((unsigned short)(sv >> 16));
    int e = beg;
    for (; e + 8 <= end; e += 8) {
      int idx = csr[e + li];  // 8 indices, one per lane
#pragma unroll
      for (int j = 0; j < 8; j++) {
        int sj = __shfl(idx, j, 8);
        unsigned int v = xsl[(size_t)sj * 8 + li];
        ax += b2f((unsigned short)(v & 0xffff));
        ay += b2f((unsigned short)(v >> 16));
      }
    }
    if (e < end) {
      int last = end - 1;
      int ce = e + li;
      int idx = csr[(ce < end) ? ce : last];
      int rem = end - e;
      for (int j = 0; j < rem; j++) {
        int sj = __shfl(idx, j, 8);
        unsigned int v = xsl[(size_t)sj * 8 + li];
        ax += b2f((unsigned short)(v & 0xffff));
        ay += b2f((unsigned short)(v >> 16));
      }
    }
    asl[(size_t)n * 8 + li] = (unsigned int)f2b(ax) | ((unsigned int)f2b(ay) << 16);
  }
}

// ---------------- H = relu(A @ W + b) via MFMA; A and H in sliced layout ----------------
__global__ __launch_bounds__(256) void gemm_mfma(const unsigned int* __restrict__ A,
                                                 const unsigned short* __restrict__ Wt,
                                                 const float* __restrict__ bias,
                                                 unsigned short* __restrict__ H) {
  __shared__ uint4 a_sh4[1024];  // 16KB: A tile [64][256B] swizzled
  __shared__ uint4 w_sh4[2048];  // 32KB: Wt [128][256B] swizzled; reused as f32 out
  char* a_sh = (char*)a_sh4;
  char* w_sh = (char*)w_sh4;
  const int t = threadIdx.x;
  const int block_row = blockIdx.x * 64;

  // stage Wt (8 passes of 4KB)
#pragma unroll
  for (int p = 0; p < 8; p++) {
    int lin = p * 4096 + t * 16;
    int row = lin >> 8, inner = lin & 255;
    uint4 v = *(const uint4*)((const char*)Wt + lin);
    *(uint4*)(w_sh + row * 256 + (inner ^ ((row & 7) << 4))) = v;
  }
  // stage A tile from sliced layout (4 passes of 4KB)
#pragma unroll
  for (int p = 0; p < 4; p++) {
    int lin = p * 4096 + t * 16;
    int row = lin >> 8, inner = lin & 255;
    int grow = block_row + row;
    uint4 v = make_uint4(0u, 0u, 0u, 0u);
    if (grow < NN) {
      int slice = inner >> 5, half = (inner >> 4) & 1;
      v = *(const uint4*)(A + ((size_t)slice * NN + grow) * 8 + half * 4);
    }
    *(uint4*)(a_sh + row * 256 + (inner ^ ((row & 7) << 4))) = v;
  }
  __syncthreads();

  const int wid = t >> 6, lane = t & 63;
  const int rowbase = wid * 16;
  const int lr = lane & 15, lk = lane >> 4;

  f32x4 acc[8];
#pragma unroll
  for (int i = 0; i < 8; i++) acc[i] = (f32x4){0.f, 0.f, 0.f, 0.f};

#pragma unroll
  for (int c = 0; c < 4; c++) {
    int arow = rowbase + lr;
    bf16x8 af = *(const bf16x8*)(a_sh + arow * 256 + ((c * 64 + lk * 16) ^ ((arow & 7) << 4)));
#pragma unroll
    for (int nt = 0; nt < 8; nt++) {
      int bcol = nt * 16 + lr;
      bf16x8 bf = *(const bf16x8*)(w_sh + bcol * 256 + ((c * 64 + lk * 16) ^ ((bcol & 7) << 4)));
      acc[nt] = __builtin_amdgcn_mfma_f32_16x16x32_bf16(af, bf, acc[nt], 0, 0, 0);
    }
  }
  __syncthreads();  // all waves done reading w_sh

  // bias + relu, stage f32 output in w_sh as [64][128]
  float* osh = (float*)w_sh;
#pragma unroll
  for (int nt = 0; nt < 8; nt++) {
    int col = nt * 16 + lr;
    float bv = bias[col];
#pragma unroll
    for (int r = 0; r < 4; r++) {
      int row = rowbase + lk * 4 + r;
      osh[row * 128 + col] = fmaxf(acc[nt][r] + bv, 0.f);
    }
  }
  __syncthreads();

  // convert to bf16, store in sliced layout
#pragma unroll
  for (int i = 0; i < 8; i++) {
    int fidx = i * 1024 + t * 4;
    float4 v = *(const float4*)(osh + fidx);
    int row = fidx >> 7, col = fidx & 127;
    int grow = block_row + row;
    if (grow < NN) {
      int slice = col >> 4, w = col & 15;
      ushort4 o;
      o.x = f2b(v.x); o.y = f2b(v.y); o.z = f2b(v.z); o.w = f2b(v.w);
      *(ushort4*)(H + ((size_t)slice * NN + grow) * 16 + w) = o;
    }
  }
}

// ---------------- per-graph sum (sliced bf16 input, sorted graph_id) ----------------
__global__ __launch_bounds__(128) void pool_partial(const unsigned short* __restrict__ H,
                                                    const int* __restrict__ gid,
                                                    float* __restrict__ sums,
                                                    float* __restrict__ cnts) {
  const int CHUNK = 256;
  int start = blockIdx.x * CHUNK;
  int end = start + CHUNK;
  if (end > NN) end = NN;
  if (start >= NN) return;
  int f = threadIdx.x;
  const unsigned short* Hf = H + (size_t)(f >> 4) * NN * 16 + (f & 15);
  float acc = 0.f;
  int cnt = 0;
  int cur = gid[start];
  for (int n = start; n < end; n++) {
    int g = gid[n];
    if (g != cur) {
      unsafeAtomicAdd(&sums[cur * DD + f], acc);
      if (f == 0) unsafeAtomicAdd(&cnts[cur], (float)cnt);
      acc = 0.f;
      cnt = 0;
      cur = g;
    }
    acc += b2f(Hf[(size_t)n * 16]);
    cnt++;
  }
  unsafeAtomicAdd(&sums[cur * DD + f], acc);
  if (f == 0) unsafeAtomicAdd(&cnts[cur], (float)cnt);
}

// ---------------- head ----------------
__global__ __launch_bounds__(512) void head(const float* __restrict__ sums,
                                            const float* __restrict__ cnts,
                                            const float* __restrict__ Wp,
                                            const float* __restrict__ bp,
                                            float* __restrict__ out) {
  int t = threadIdx.x;
  int g = t >> 3;
  int v = t & 7;
  float cnt = cnts[g];
  if (cnt < 1.f) cnt = 1.f;
  float acc = 0.f;
  for (int d = 0; d < DD; d++) acc += sums[g * DD + d] * Wp[d * NV + v];
  out[t] = acc / cnt + bp[v];
}

// ---------------- launch ----------------
extern "C" void kernel_launch(void* const* d_in, const int* in_sizes, int n_in,
                              void* d_out, int out_size, void* d_ws, size_t ws_size,
                              hipStream_t stream) {
  const float* feat = (const float*)d_in[0];
  const int* src = (const int*)d_in[1];
  const int* dst = (const int*)d_in[2];
  const int* gid = (const int*)d_in[3];
  const float* W1 = (const float*)d_in[4];
  const float* b1 = (const float*)d_in[5];
  const float* W2 = (const float*)d_in[6];
  const float* b2 = (const float*)d_in[7];
  const float* W3 = (const float*)d_in[8];
  const float* b3 = (const float*)d_in[9];
  const float* Wp = (const float*)d_in[10];
  const float* bp = (const float*)d_in[11];
  float* out = (float*)d_out;

  char* ws = (char*)d_ws;
  const size_t matb = (size_t)NN * DD;  // bf16 elements per matrix
  unsigned short* xs0 = (unsigned short*)ws;   // sliced
  unsigned short* aggs = xs0 + matb;           // sliced
  unsigned short* hs = aggs + matb;            // sliced
  unsigned short* wtb = hs + matb;             // 3 * 16384
  float* sums = (float*)(wtb + 3 * DD * DD);
  float* cnts = sums + NG * DD;
  int* deg = (int*)(cnts + NG);
  int* rowp = deg + NN;          // NN+1 entries
  int* cursor = rowp + NN + 1;
  int* bsum = cursor + NN;
  int* csr = bsum + 128;

  zero_f<<<(NG * DD + NG + 255) / 256, 256, 0, stream>>>(sums, NG * DD + NG);
  zero_i<<<(NN + 255) / 256, 256, 0, stream>>>(deg, NN);

  // conversions (sliced feature layout)
  cvt_feat<<<(NN * NS + 255) / 256, 256, 0, stream>>>(feat, (unsigned int*)xs0);
  cvt_wt3<<<192, 256, 0, stream>>>(W1, W2, W3, wtb);

  // CSR build (edges grouped by dst)
  hist_dst<<<(NE + 255) / 256, 256, 0, stream>>>(dst, deg);
  scan1<<<SCAN_NB, 256, 0, stream>>>(deg, rowp, bsum);
  scan2<<<1, 128, 0, stream>>>(bsum, SCAN_NB);
  scan3<<<(NN + 255) / 256, 256, 0, stream>>>(rowp, bsum, cursor);
  fill_csr<<<(NE + 255) / 256, 256, 0, stream>>>(src, dst, cursor, csr);

  const int ggrid = NCHUNK * NS;  // 1568
  const int mgrid = (NN + 63) / 64;
  // L1: xs0 -> aggs -> hs
  gather_slice<<<ggrid, 256, 0, stream>>>((const unsigned int*)xs0, csr, rowp, (unsigned int*)aggs);
  gemm_mfma<<<mgrid, 256, 0, stream>>>((const unsigned int*)aggs, wtb, b1, hs);
  // L2: hs -> aggs -> xs0
  gather_slice<<<ggrid, 256, 0, stream>>>((const unsigned int*)hs, csr, rowp, (unsigned int*)aggs);
  gemm_mfma<<<mgrid, 256, 0, stream>>>((const unsigned int*)aggs, wtb + DD * DD, b2, xs0);
  // L3: xs0 -> aggs -> hs
  gather_slice<<<ggrid, 256, 0, stream>>>((const unsigned int*)xs0, csr, rowp, (unsigned int*)aggs);
  gemm_mfma<<<mgrid, 256, 0, stream>>>((const unsigned int*)aggs, wtb + 2 * DD * DD, b3, hs);

  pool_partial<<<(NN + 255) / 256, 128, 0, stream>>>(hs, gid, sums, cnts);
  head<<<1, 512, 0, stream>>>(sums, cnts, Wp, bp, out);
}

// Round 6
// 350.848 us; speedup vs baseline: 6.5004x; 1.2139x over previous
//
#include <hip/hip_runtime.h>
#include <cstddef>

#define NN 100000
#define NE 800000
#define NG 64
#define DD 128
#define NV 8
#define NS 8           // column slices (16 bf16 = 32B each)
#define SCAN_CH 1024
#define SCAN_NB ((NN + SCAN_CH - 1) / SCAN_CH)  // 98
#define NPC 512        // dst nodes per gather chunk
#define NCHUNK ((NN + NPC - 1) / NPC)           // 196

#define CVT_BLKS 6250   // NN*16/256
#define WT_BLKS 192     // 3*16384/256
#define HIST_BLKS 3125  // NE/256

typedef __attribute__((ext_vector_type(8))) short bf16x8;
typedef __attribute__((ext_vector_type(4))) float f32x4;

// ---------------- bf16 helpers ----------------
__device__ inline float lo2f(unsigned int u) {
  union { unsigned int i; float f; } x;
  x.i = u << 16;
  return x.f;
}
__device__ inline float hi2f(unsigned int u) {
  union { unsigned int i; float f; } x;
  x.i = u & 0xffff0000u;
  return x.f;
}
__device__ inline unsigned short f2b(float f) {
  union { float f; unsigned int i; } x;
  x.f = f;
  unsigned int r = x.i + 0x7fffu + ((x.i >> 16) & 1u);
  return (unsigned short)(r >> 16);
}
__device__ inline unsigned int pk(float a, float b) {
  return (unsigned int)f2b(a) | ((unsigned int)f2b(b) << 16);
}

// ---------------- zero (sums+cnts+deg are contiguous 4B words) ----------------
__global__ __launch_bounds__(256) void zero_w(unsigned int* __restrict__ p, int n) {
  int i = blockIdx.x * blockDim.x + threadIdx.x;
  if (i < n) p[i] = 0u;
}

// ---------------- prep: cvt_feat (sliced) + cvt_wt3 + hist_dst ----------------
__global__ __launch_bounds__(256) void prep(const float* __restrict__ feat,
                                            const float* __restrict__ W1,
                                            const float* __restrict__ W2,
                                            const float* __restrict__ W3,
                                            const int* __restrict__ dst,
                                            unsigned short* __restrict__ xs,
                                            unsigned short* __restrict__ Wt,
                                            int* __restrict__ deg) {
  int b = blockIdx.x;
  if (b < CVT_BLKS) {
    // features f32 -> bf16 sliced: xs[s][n][16]
    int tid = b * 256 + threadIdx.x;  // 0 .. 1.6M
    int n = tid >> 4, part = tid & 15;
    const float* p = feat + (size_t)n * DD + part * 8;
    float4 v0 = *(const float4*)p;
    float4 v1 = *(const float4*)(p + 4);
    unsigned int u0 = pk(v0.x, v0.y), u1 = pk(v0.z, v0.w);
    unsigned int u2 = pk(v1.x, v1.y), u3 = pk(v1.z, v1.w);
    int slice = part >> 1, half = part & 1;
    *(uint4*)((char*)xs + ((size_t)slice * NN + n) * 32 + half * 16) =
        make_uint4(u0, u1, u2, u3);
  } else if (b < CVT_BLKS + WT_BLKS) {
    // W[k][n] f32 -> Wt[n][k] bf16, all three
    int idx = (b - CVT_BLKS) * 256 + threadIdx.x;
    int w = idx >> 14, r = idx & 16383;
    const float* W = (w == 0) ? W1 : (w == 1) ? W2 : W3;
    Wt[idx] = f2b(W[(r & 127) * DD + (r >> 7)]);
  } else {
    int e = (b - CVT_BLKS - WT_BLKS) * 256 + threadIdx.x;
    if (e < NE) atomicAdd(&deg[dst[e]], 1);
  }
}

// ---------------- CSR scans ----------------
__global__ __launch_bounds__(256) void scan1(const int* __restrict__ deg,
                                             int* __restrict__ excl,
                                             int* __restrict__ bsum) {
  __shared__ int ts[256];
  int base = blockIdx.x * SCAN_CH;
  int t = threadIdx.x;
  int v[4];
  int s = 0;
#pragma unroll
  for (int i = 0; i < 4; i++) {
    int idx = base + t * 4 + i;
    v[i] = (idx < NN) ? deg[idx] : 0;
    s += v[i];
  }
  ts[t] = s;
  __syncthreads();
  for (int off = 1; off < 256; off <<= 1) {
    int val = (t >= off) ? ts[t - off] : 0;
    __syncthreads();
    ts[t] += val;
    __syncthreads();
  }
  if (t == 255) bsum[blockIdx.x] = ts[255];
  int run = ts[t] - s;
#pragma unroll
  for (int i = 0; i < 4; i++) {
    int idx = base + t * 4 + i;
    if (idx < NN) excl[idx] = run;
    run += v[i];
  }
}

__global__ __launch_bounds__(128) void scan2(int* __restrict__ bsum, int nb) {
  __shared__ int sh[128];
  int t = threadIdx.x;
  int v = (t < nb) ? bsum[t] : 0;
  sh[t] = v;
  __syncthreads();
  for (int off = 1; off < 128; off <<= 1) {
    int u = (t >= off) ? sh[t - off] : 0;
    __syncthreads();
    sh[t] += u;
    __syncthreads();
  }
  if (t < nb) bsum[t] = sh[t] - v;  // exclusive
}

__global__ __launch_bounds__(256) void scan3(int* __restrict__ rowp,
                                             const int* __restrict__ bsum,
                                             int* __restrict__ cursor) {
  int i = blockIdx.x * blockDim.x + threadIdx.x;
  if (i < NN) {
    int v = rowp[i] + bsum[i / SCAN_CH];
    rowp[i] = v;
    cursor[i] = v;
  }
  if (i == 0) rowp[NN] = NE;
}

__global__ __launch_bounds__(256) void fill_csr(const int* __restrict__ src,
                                                const int* __restrict__ dst,
                                                int* __restrict__ cursor,
                                                int* __restrict__ csr) {
  int e = blockIdx.x * blockDim.x + threadIdx.x;
  if (e < NE) {
    int pos = atomicAdd(&cursor[dst[e]], 1);
    csr[pos] = src[e];
  }
}

// ---------------- sliced gather -> row-major agg ----------------
// slice = blockIdx.x & 7 pins each 3.2MB slice to one XCD's L2.
// 4-lane groups, uint2 (8B) per lane; 32-bit byte offsets.
__global__ __launch_bounds__(256) void gather_slice(const unsigned short* __restrict__ xs,
                                                    const int* __restrict__ csr,
                                                    const int* __restrict__ rowp,
                                                    unsigned short* __restrict__ agg) {
  const int s = blockIdx.x & 7;
  const int chunk = blockIdx.x >> 3;
  const char* __restrict__ xsl = (const char*)xs + (size_t)s * NN * 32;
  char* __restrict__ aggp = (char*)agg + s * 32;
  const int li = threadIdx.x & 3;
  const int grp = threadIdx.x >> 2;  // 0..63
  const int node0 = chunk * NPC;
  int node1 = node0 + NPC;
  if (node1 > NN) node1 = NN;
  const int lo8 = li * 8;
  for (int n = node0 + grp; n < node1; n += 64) {
    int beg = rowp[n], end = rowp[n + 1];
    uint2 sv = *(const uint2*)(xsl + n * 32 + lo8);
    float a0 = lo2f(sv.x), a1 = hi2f(sv.x), a2 = lo2f(sv.y), a3 = hi2f(sv.y);
    int e = beg;
    for (; e + 4 <= end; e += 4) {
      int idx = csr[e + li];
#pragma unroll
      for (int j = 0; j < 4; j++) {
        int sj = __shfl(idx, j, 4);
        uint2 v = *(const uint2*)(xsl + sj * 32 + lo8);
        a0 += lo2f(v.x);
        a1 += hi2f(v.x);
        a2 += lo2f(v.y);
        a3 += hi2f(v.y);
      }
    }
    if (e < end) {
      int ce = e + li;
      int idx = csr[(ce < end) ? ce : end - 1];
      int rem = end - e;
      for (int j = 0; j < rem; j++) {
        int sj = __shfl(idx, j, 4);
        uint2 v = *(const uint2*)(xsl + sj * 32 + lo8);
        a0 += lo2f(v.x);
        a1 += hi2f(v.x);
        a2 += lo2f(v.y);
        a3 += hi2f(v.y);
      }
    }
    uint2 o;
    o.x = pk(a0, a1);
    o.y = pk(a2, a3);
    *(uint2*)(aggp + (size_t)n * 256 + lo8) = o;
  }
}

// ---------------- H = relu(A @ W + b) via MFMA ----------------
// A row-major bf16 [NN][128]; H written sliced (POOL=0) or pooled (POOL=1, no H write)
template <int POOL>
__global__ __launch_bounds__(256) void gemm_mfma(const unsigned short* __restrict__ A,
                                                 const unsigned short* __restrict__ Wt,
                                                 const float* __restrict__ bias,
                                                 unsigned short* __restrict__ H,
                                                 const int* __restrict__ gid,
                                                 float* __restrict__ sums,
                                                 float* __restrict__ cnts) {
  __shared__ uint4 a_sh4[1024];  // 16KB: A tile [64][256B] swizzled
  __shared__ uint4 w_sh4[2048];  // 32KB: Wt [128][256B] swizzled; reused as f32 out
  __shared__ int gsh[64];
  char* a_sh = (char*)a_sh4;
  char* w_sh = (char*)w_sh4;
  const int t = threadIdx.x;
  const int block_row = blockIdx.x * 64;

  if (POOL) {
    if (t < 64) gsh[t] = (block_row + t < NN) ? gid[block_row + t] : -1;
  }

  // stage Wt (8 passes of 4KB)
#pragma unroll
  for (int p = 0; p < 8; p++) {
    int lin = p * 4096 + t * 16;
    int row = lin >> 8, inner = lin & 255;
    uint4 v = *(const uint4*)((const char*)Wt + lin);
    *(uint4*)(w_sh + row * 256 + (inner ^ ((row & 7) << 4))) = v;
  }
  // stage A tile, row-major source (4 passes of 4KB)
#pragma unroll
  for (int p = 0; p < 4; p++) {
    int lin = p * 4096 + t * 16;
    int row = lin >> 8, inner = lin & 255;
    int grow = block_row + row;
    uint4 v = make_uint4(0u, 0u, 0u, 0u);
    if (grow < NN) v = *(const uint4*)((const char*)A + (size_t)grow * 256 + inner);
    *(uint4*)(a_sh + row * 256 + (inner ^ ((row & 7) << 4))) = v;
  }
  __syncthreads();

  const int wid = t >> 6, lane = t & 63;
  const int rowbase = wid * 16;
  const int lr = lane & 15, lk = lane >> 4;

  f32x4 acc[8];
#pragma unroll
  for (int i = 0; i < 8; i++) acc[i] = (f32x4){0.f, 0.f, 0.f, 0.f};

#pragma unroll
  for (int c = 0; c < 4; c++) {
    int arow = rowbase + lr;
    bf16x8 af = *(const bf16x8*)(a_sh + arow * 256 + ((c * 64 + lk * 16) ^ ((arow & 7) << 4)));
#pragma unroll
    for (int nt = 0; nt < 8; nt++) {
      int bcol = nt * 16 + lr;
      bf16x8 bf = *(const bf16x8*)(w_sh + bcol * 256 + ((c * 64 + lk * 16) ^ ((bcol & 7) << 4)));
      acc[nt] = __builtin_amdgcn_mfma_f32_16x16x32_bf16(af, bf, acc[nt], 0, 0, 0);
    }
  }
  __syncthreads();  // all waves done reading w_sh

  // bias + relu, stage f32 output in w_sh as [64][128]
  float* osh = (float*)w_sh;
#pragma unroll
  for (int nt = 0; nt < 8; nt++) {
    int col = nt * 16 + lr;
    float bv = bias[col];
#pragma unroll
    for (int r = 0; r < 4; r++) {
      int row = rowbase + lk * 4 + r;
      osh[row * 128 + col] = fmaxf(acc[nt][r] + bv, 0.f);
    }
  }
  __syncthreads();

  if (POOL == 0) {
    // convert to bf16, store in sliced layout
#pragma unroll
    for (int i = 0; i < 8; i++) {
      int fidx = i * 1024 + t * 4;
      float4 v = *(const float4*)(osh + fidx);
      int row = fidx >> 7, col = fidx & 127;
      int grow = block_row + row;
      if (grow < NN) {
        int slice = col >> 4, w = col & 15;
        ushort4 o;
        o.x = f2b(v.x);
        o.y = f2b(v.y);
        o.z = f2b(v.z);
        o.w = f2b(v.w);
        *(ushort4*)(H + ((size_t)slice * NN + grow) * 16 + w) = o;
      }
    }
  } else {
    // fused per-graph pooling from f32 LDS (gid sorted)
    if (t < 128) {
      int f = t;
      float acc2 = 0.f;
      int cnt = 0;
      int cur = gsh[0];
      for (int r = 0; r < 64; r++) {
        int g = gsh[r];
        if (g < 0) break;
        if (g != cur) {
          unsafeAtomicAdd(&sums[cur * DD + f], acc2);
          if (f == 0) unsafeAtomicAdd(&cnts[cur], (float)cnt);
          acc2 = 0.f;
          cnt = 0;
          cur = g;
        }
        acc2 += osh[r * 128 + f];
        cnt++;
      }
      if (cur >= 0 && cnt > 0) {
        unsafeAtomicAdd(&sums[cur * DD + f], acc2);
        if (f == 0) unsafeAtomicAdd(&cnts[cur], (float)cnt);
      }
    }
  }
}

// ---------------- head ----------------
__global__ __launch_bounds__(512) void head(const float* __restrict__ sums,
                                            const float* __restrict__ cnts,
                                            const float* __restrict__ Wp,
                                            const float* __restrict__ bp,
                                            float* __restrict__ out) {
  int t = threadIdx.x;
  int g = t >> 3;
  int v = t & 7;
  float cnt = cnts[g];
  if (cnt < 1.f) cnt = 1.f;
  float acc = 0.f;
  for (int d = 0; d < DD; d++) acc += sums[g * DD + d] * Wp[d * NV + v];
  out[t] = acc / cnt + bp[v];
}

// ---------------- launch ----------------
extern "C" void kernel_launch(void* const* d_in, const int* in_sizes, int n_in,
                              void* d_out, int out_size, void* d_ws, size_t ws_size,
                              hipStream_t stream) {
  const float* feat = (const float*)d_in[0];
  const int* src = (const int*)d_in[1];
  const int* dst = (const int*)d_in[2];
  const int* gid = (const int*)d_in[3];
  const float* W1 = (const float*)d_in[4];
  const float* b1 = (const float*)d_in[5];
  const float* W2 = (const float*)d_in[6];
  const float* b2 = (const float*)d_in[7];
  const float* W3 = (const float*)d_in[8];
  const float* b3 = (const float*)d_in[9];
  const float* Wp = (const float*)d_in[10];
  const float* bp = (const float*)d_in[11];
  float* out = (float*)d_out;

  char* ws = (char*)d_ws;
  const size_t matb = (size_t)NN * DD;  // bf16 elements per matrix
  unsigned short* xs0 = (unsigned short*)ws;  // sliced
  unsigned short* hs = xs0 + matb;            // sliced
  unsigned short* agg = hs + matb;            // row-major
  unsigned short* wtb = agg + matb;           // 3 * 16384
  float* sums = (float*)(wtb + 3 * DD * DD);
  float* cnts = sums + NG * DD;
  int* deg = (int*)(cnts + NG);               // contiguous with sums/cnts for zeroing
  int* rowp = deg + NN;                       // NN+1 entries
  int* cursor = rowp + NN + 1;
  int* bsum = cursor + NN;
  int* csr = bsum + 128;

  const int nzero = NG * DD + NG + NN;  // sums + cnts + deg (4B words)
  zero_w<<<(nzero + 255) / 256, 256, 0, stream>>>((unsigned int*)sums, nzero);

  prep<<<CVT_BLKS + WT_BLKS + HIST_BLKS, 256, 0, stream>>>(feat, W1, W2, W3, dst, xs0, wtb, deg);

  scan1<<<SCAN_NB, 256, 0, stream>>>(deg, rowp, bsum);
  scan2<<<1, 128, 0, stream>>>(bsum, SCAN_NB);
  scan3<<<(NN + 255) / 256, 256, 0, stream>>>(rowp, bsum, cursor);
  fill_csr<<<(NE + 255) / 256, 256, 0, stream>>>(src, dst, cursor, csr);

  const int ggrid = NCHUNK * NS;  // 1568
  const int mgrid = (NN + 63) / 64;
  // L1: xs0 -> agg -> hs
  gather_slice<<<ggrid, 256, 0, stream>>>(xs0, csr, rowp, agg);
  gemm_mfma<0><<<mgrid, 256, 0, stream>>>(agg, wtb, b1, hs, nullptr, nullptr, nullptr);
  // L2: hs -> agg -> xs0
  gather_slice<<<ggrid, 256, 0, stream>>>(hs, csr, rowp, agg);
  gemm_mfma<0><<<mgrid, 256, 0, stream>>>(agg, wtb + DD * DD, b2, xs0, nullptr, nullptr, nullptr);
  // L3: xs0 -> agg -> pooled
  gather_slice<<<ggrid, 256, 0, stream>>>(xs0, csr, rowp, agg);
  gemm_mfma<1><<<mgrid, 256, 0, stream>>>(agg, wtb + 2 * DD * DD, b3, nullptr, gid, sums, cnts);

  head<<<1, 512, 0, stream>>>(sums, cnts, Wp, bp, out);
}